// Round 1
// 299.336 us; speedup vs baseline: 1.0310x; 1.0310x over previous
//
#include <hip/hip_runtime.h>

#define NH 128
#define NW 128
#define ND 128
#define HWD (NH * NW * ND)
#define NWD (NW * ND)
#define NB 2

__global__ __launch_bounds__(256) void warp_dti_kernel(
    const float* __restrict__ dti,
    const float* __restrict__ ddf,
    float* __restrict__ out)
{
    // Block-uniform decomposition: 8192 blocks per batch, each block = one h row-pair span
    // sp = h*16384 + w*128 + d ; block covers (h, w..w+1, d 0..127)
    const int blk   = blockIdx.x;
    const int b     = blk >> 13;              // scalar (SGPR)
    const int blkin = blk & 8191;
    const int tid   = threadIdx.x;
    const int sp    = (blkin << 8) | tid;
    const int d     = tid & (ND - 1);
    const int w     = ((blkin & 63) << 1) | (tid >> 7);  // wave-uniform
    const int h     = blkin >> 6;             // scalar (SGPR)

    const int dbase = b * 3 * HWD;            // scalar

    // ---- phase 1: issue ALL ddf loads (center + 6 clamped-offset neighbors per channel)
    const int oh_m = (h > 0)      ? -NWD : 0;     // scalar
    const int oh_p = (h < NH - 1) ?  NWD : 0;     // scalar
    const int ow_m = (w > 0)      ? -ND  : 0;     // wave-uniform
    const int ow_p = (w < NW - 1) ?  ND  : 0;     // wave-uniform
    const int od_m = (d > 0)      ? -1   : 0;     // per-lane (cndmask)
    const int od_p = (d < ND - 1) ?  1   : 0;

    float uc[3], hm[3], hp[3], wm[3], wp[3], dm[3], dp[3];
#pragma unroll
    for (int c = 0; c < 3; ++c) {
        const float* p = ddf + dbase + c * HWD;
        uc[c] = p[sp];                          // centers first (coords dep)
    }
#pragma unroll
    for (int c = 0; c < 3; ++c) {
        const float* p = ddf + dbase + c * HWD;
        hm[c] = p[sp + oh_m];  hp[c] = p[sp + oh_p];
        wm[c] = p[sp + ow_m];  wp[c] = p[sp + ow_p];
        dm[c] = p[sp + od_m];  dp[c] = p[sp + od_p];
    }

    // ---- coords / corner addresses (depends only on uc) ----
    const float cx = (float)h + uc[0];
    const float cy = (float)w + uc[1];
    const float cz = (float)d + uc[2];
    const float flx = floorf(cx), fly = floorf(cy), flz = floorf(cz);
    const float fx = cx - flx, fy = cy - fly, fz = cz - flz;
    const int x0 = (int)flx, y0 = (int)fly, z0 = (int)flz;
    const int xa = min(max(x0,     0), NH - 1), xb = min(max(x0 + 1, 0), NH - 1);
    const int ya = min(max(y0,     0), NW - 1), yb = min(max(y0 + 1, 0), NW - 1);
    const int za = min(max(z0,     0), ND - 1), zb = min(max(z0 + 1, 0), ND - 1);

    const int raa = (xa * NW + ya) * ND;
    const int rab = (xa * NW + yb) * ND;
    const int rba = (xb * NW + ya) * ND;
    const int rbb = (xb * NW + yb) * ND;

    int lin[8];
    lin[0] = raa + za; lin[1] = raa + zb;
    lin[2] = rab + za; lin[3] = rab + zb;
    lin[4] = rba + za; lin[5] = rba + zb;
    lin[6] = rbb + za; lin[7] = rbb + zb;

    // ---- phase 2: issue all 48 gather loads; consumed only AFTER Newton ----
    const int ibase = b * 6 * HWD;            // scalar
    float g[8][6];
#pragma unroll
    for (int c = 0; c < 8; ++c)
#pragma unroll
        for (int ch = 0; ch < 6; ++ch)
            g[c][ch] = dti[ibase + ch * HWD + lin[c]];

    // Pin the gathers above; Newton below executes in their latency shadow.
    __builtin_amdgcn_sched_barrier(0);

    // ---- gradient -> A = I + grad(ddf)  (jnp.gradient semantics, branch-free) ----
    const float sh = (oh_m == 0 || oh_p == 0) ? 1.0f : 0.5f;   // scalar
    const float sw = (ow_m == 0 || ow_p == 0) ? 1.0f : 0.5f;   // wave-uniform
    const float sd = (od_m == 0 || od_p == 0) ? 1.0f : 0.5f;   // cndmask

    float U[3][3];
#pragma unroll
    for (int c = 0; c < 3; ++c) {
        U[c][0] = sh * (hp[c] - hm[c]);
        U[c][1] = sw * (wp[c] - wm[c]);
        U[c][2] = sd * (dp[c] - dm[c]);
    }
    U[0][0] += 1.0f; U[1][1] += 1.0f; U[2][2] += 1.0f;

    // ---- Newton polar: U <- 0.5*(zeta*U + inv((zeta*U)^T)), divide-free ----
#pragma unroll
    for (int it = 0; it < 6; ++it) {
        float c00 = U[1][1]*U[2][2] - U[1][2]*U[2][1];
        float c01 = U[0][2]*U[2][1] - U[0][1]*U[2][2];
        float c02 = U[0][1]*U[1][2] - U[0][2]*U[1][1];
        float c10 = U[1][2]*U[2][0] - U[1][0]*U[2][2];
        float c11 = U[0][0]*U[2][2] - U[0][2]*U[2][0];
        float c12 = U[0][2]*U[1][0] - U[0][0]*U[1][2];
        float c20 = U[1][0]*U[2][1] - U[1][1]*U[2][0];
        float c21 = U[0][1]*U[2][0] - U[0][0]*U[2][1];
        float c22 = U[0][0]*U[1][1] - U[0][1]*U[1][0];
        float det = U[0][0]*c00 + U[0][1]*c10 + U[0][2]*c20;

        float l    = __log2f(fabsf(det));                              // v_log_f32
        float zeta = __builtin_amdgcn_exp2f(-0.33333333333333333f * l); // v_exp_f32
        float s    = copysignf(zeta * zeta, det);
        float hz = 0.5f * zeta;
        float hs = 0.5f * s;

        float n00 = hz*U[0][0] + c00*hs;
        float n01 = hz*U[0][1] + c10*hs;
        float n02 = hz*U[0][2] + c20*hs;
        float n10 = hz*U[1][0] + c01*hs;
        float n11 = hz*U[1][1] + c11*hs;
        float n12 = hz*U[1][2] + c21*hs;
        float n20 = hz*U[2][0] + c02*hs;
        float n21 = hz*U[2][1] + c12*hs;
        float n22 = hz*U[2][2] + c22*hs;
        U[0][0]=n00; U[0][1]=n01; U[0][2]=n02;
        U[1][0]=n10; U[1][1]=n11; U[1][2]=n12;
        U[2][0]=n20; U[2][1]=n21; U[2][2]=n22;
    }

    // ---- trilinear accumulate (gathers have landed by now) ----
    const float wxa = 1.0f - fx, wya = 1.0f - fy, wza = 1.0f - fz;
    float wc[8];
    wc[0] = (wxa * wya) * wza;  wc[1] = (wxa * wya) * fz;
    wc[2] = (wxa * fy)  * wza;  wc[3] = (wxa * fy)  * fz;
    wc[4] = (fx  * wya) * wza;  wc[5] = (fx  * wya) * fz;
    wc[6] = (fx  * fy)  * wza;  wc[7] = (fx  * fy)  * fz;

    float acc[6] = {0.f, 0.f, 0.f, 0.f, 0.f, 0.f};
#pragma unroll
    for (int c = 0; c < 8; ++c)
#pragma unroll
        for (int ch = 0; ch < 6; ++ch)
            acc[ch] = fmaf(wc[c], g[c][ch], acc[ch]);

    // ---- T = R^T D R, output lower-tri ----
    float Dm[3][3];
    Dm[0][0] = acc[0]; Dm[0][1] = acc[1]; Dm[0][2] = acc[3];
    Dm[1][0] = acc[1]; Dm[1][1] = acc[2]; Dm[1][2] = acc[4];
    Dm[2][0] = acc[3]; Dm[2][1] = acc[4]; Dm[2][2] = acc[5];

    float M[3][3];
#pragma unroll
    for (int i = 0; i < 3; ++i)
#pragma unroll
        for (int k = 0; k < 3; ++k)
            M[i][k] = U[0][i]*Dm[0][k] + U[1][i]*Dm[1][k] + U[2][i]*Dm[2][k];

    float T00 = M[0][0]*U[0][0] + M[0][1]*U[1][0] + M[0][2]*U[2][0];
    float T10 = M[1][0]*U[0][0] + M[1][1]*U[1][0] + M[1][2]*U[2][0];
    float T11 = M[1][0]*U[0][1] + M[1][1]*U[1][1] + M[1][2]*U[2][1];
    float T20 = M[2][0]*U[0][0] + M[2][1]*U[1][0] + M[2][2]*U[2][0];
    float T21 = M[2][0]*U[0][1] + M[2][1]*U[1][1] + M[2][2]*U[2][1];
    float T22 = M[2][0]*U[0][2] + M[2][1]*U[1][2] + M[2][2]*U[2][2];

    const int obase = b * 6 * HWD;            // scalar
    out[obase + 0 * HWD + sp] = T00;
    out[obase + 1 * HWD + sp] = T10;
    out[obase + 2 * HWD + sp] = T11;
    out[obase + 3 * HWD + sp] = T20;
    out[obase + 4 * HWD + sp] = T21;
    out[obase + 5 * HWD + sp] = T22;
}

extern "C" void kernel_launch(void* const* d_in, const int* in_sizes, int n_in,
                              void* d_out, int out_size, void* d_ws, size_t ws_size,
                              hipStream_t stream) {
    const float* dti = (const float*)d_in[0];
    const float* ddf = (const float*)d_in[1];
    float* o = (float*)d_out;
    const int n = NB * HWD;   // 4,194,304 voxels
    warp_dti_kernel<<<n / 256, 256, 0, stream>>>(dti, ddf, o);
}

// Round 2
// 265.460 us; speedup vs baseline: 1.1626x; 1.1276x over previous
//
#include <hip/hip_runtime.h>

#define NH 128
#define NW 128
#define ND 128
#define HWD (NH * NW * ND)
#define NWD (NW * ND)
#define NB 2

typedef float f32x2 __attribute__((ext_vector_type(2)));

__global__ __launch_bounds__(256) void warp_dti_kernel(
    const float* __restrict__ dti,
    const float* __restrict__ ddf,
    float* __restrict__ out)
{
    // Block-uniform decomposition: blkin = h*64 + (w>>1); block covers (h, 2w, d 0..127)
    const int blk   = blockIdx.x;
    const int b     = blk >> 13;              // scalar (SGPR)
    const int blkin = blk & 8191;
    const int tid   = threadIdx.x;
    const int sp    = (blkin << 8) | tid;
    const int d     = tid & (ND - 1);
    const int w     = ((blkin & 63) << 1) | (tid >> 7);  // wave-uniform
    const int h     = blkin >> 6;             // scalar (SGPR)

    const int dbase = b * 3 * HWD;            // scalar

    // ---- ddf loads: center + 6 clamped-offset neighbors per channel ----
    const int oh_m = (h > 0)      ? -NWD : 0;     // scalar
    const int oh_p = (h < NH - 1) ?  NWD : 0;     // scalar
    const int ow_m = (w > 0)      ? -ND  : 0;     // wave-uniform
    const int ow_p = (w < NW - 1) ?  ND  : 0;     // wave-uniform
    const int od_m = (d > 0)      ? -1   : 0;     // per-lane
    const int od_p = (d < ND - 1) ?  1   : 0;

    float uc[3], hm[3], hp[3], wm[3], wp[3], dm[3], dp[3];
#pragma unroll
    for (int c = 0; c < 3; ++c) {
        const float* p = ddf + dbase + c * HWD;
        uc[c] = p[sp];
        hm[c] = p[sp + oh_m];  hp[c] = p[sp + oh_p];
        wm[c] = p[sp + ow_m];  wp[c] = p[sp + ow_p];
        dm[c] = p[sp + od_m];  dp[c] = p[sp + od_p];
    }

    // ---- gradient -> U = I + grad(ddf): consume ALL ddf values here so every
    //      compiler vmcnt wait stays ABOVE the asm gather issue below ----
    const float sh = (oh_m == 0 || oh_p == 0) ? 1.0f : 0.5f;
    const float sw = (ow_m == 0 || ow_p == 0) ? 1.0f : 0.5f;
    const float sd = (od_m == 0 || od_p == 0) ? 1.0f : 0.5f;

    float U[3][3];
#pragma unroll
    for (int c = 0; c < 3; ++c) {
        U[c][0] = sh * (hp[c] - hm[c]);
        U[c][1] = sw * (wp[c] - wm[c]);
        U[c][2] = sd * (dp[c] - dm[c]);
    }
    U[0][0] += 1.0f; U[1][1] += 1.0f; U[2][2] += 1.0f;

    // ---- trilinear corner setup (depends only on uc) ----
    const float cx = (float)h + uc[0];
    const float cy = (float)w + uc[1];
    const float cz = (float)d + uc[2];
    const float flx = floorf(cx), fly = floorf(cy), flz = floorf(cz);
    const float fx = cx - flx, fy = cy - fly, fz = cz - flz;
    const int x0 = (int)flx, y0 = (int)fly, z0 = (int)flz;
    const int xa = min(max(x0,     0), NH - 1), xb = min(max(x0 + 1, 0), NH - 1);
    const int ya = min(max(y0,     0), NW - 1), yb = min(max(y0 + 1, 0), NW - 1);
    // z handled as an adjacent pair: load at pa, fold the clamp into weights
    const int pa = min(max(z0, 0), ND - 2);

    unsigned voffs[4];
    voffs[0] = (unsigned)(((xa * NW + ya) * ND) + pa) * 4u;
    voffs[1] = (unsigned)(((xa * NW + yb) * ND) + pa) * 4u;
    voffs[2] = (unsigned)(((xb * NW + ya) * ND) + pa) * 4u;
    voffs[3] = (unsigned)(((xb * NW + yb) * ND) + pa) * 4u;

    const float* bases[6];
#pragma unroll
    for (int ch = 0; ch < 6; ++ch)
        bases[ch] = dti + (size_t)(b * 6 + ch) * HWD;   // scalar bases (SGPR pairs)

    // ---- pin the gather issue HERE: volatile asm cannot be sunk ----
    __builtin_amdgcn_sched_barrier(0);
    f32x2 g[6][4];
#pragma unroll
    for (int ch = 0; ch < 6; ++ch)
#pragma unroll
        for (int c = 0; c < 4; ++c)
            asm volatile("global_load_dwordx2 %0, %1, %2"
                         : "=v"(g[ch][c])
                         : "v"(voffs[c]), "s"(bases[ch]));

    // ---- Newton polar runs in the gather latency shadow (pure VALU) ----
#pragma unroll
    for (int it = 0; it < 6; ++it) {
        float c00 = U[1][1]*U[2][2] - U[1][2]*U[2][1];
        float c01 = U[0][2]*U[2][1] - U[0][1]*U[2][2];
        float c02 = U[0][1]*U[1][2] - U[0][2]*U[1][1];
        float c10 = U[1][2]*U[2][0] - U[1][0]*U[2][2];
        float c11 = U[0][0]*U[2][2] - U[0][2]*U[2][0];
        float c12 = U[0][2]*U[1][0] - U[0][0]*U[1][2];
        float c20 = U[1][0]*U[2][1] - U[1][1]*U[2][0];
        float c21 = U[0][1]*U[2][0] - U[0][0]*U[2][1];
        float c22 = U[0][0]*U[1][1] - U[0][1]*U[1][0];
        float det = U[0][0]*c00 + U[0][1]*c10 + U[0][2]*c20;

        float l    = __log2f(fabsf(det));                               // v_log_f32
        float zeta = __builtin_amdgcn_exp2f(-0.33333333333333333f * l); // v_exp_f32
        float s    = copysignf(zeta * zeta, det);
        float hz = 0.5f * zeta;
        float hs = 0.5f * s;

        float n00 = hz*U[0][0] + c00*hs;
        float n01 = hz*U[0][1] + c10*hs;
        float n02 = hz*U[0][2] + c20*hs;
        float n10 = hz*U[1][0] + c01*hs;
        float n11 = hz*U[1][1] + c11*hs;
        float n12 = hz*U[1][2] + c21*hs;
        float n20 = hz*U[2][0] + c02*hs;
        float n21 = hz*U[2][1] + c12*hs;
        float n22 = hz*U[2][2] + c22*hs;
        U[0][0]=n00; U[0][1]=n01; U[0][2]=n02;
        U[1][0]=n10; U[1][1]=n11; U[1][2]=n12;
        U[2][0]=n20; U[2][1]=n21; U[2][2]=n22;
    }

    // ---- corner weights (VALU, still in the shadow) ----
    // clamp folded into z-pair weights: value at pa gets wv0, at pa+1 gets wv1
    const float wza = 1.0f - fz, wzb = fz;
    const float wv0 = ((z0 <= ND - 2) ? wza : 0.0f) + ((z0 <= -1) ? wzb : 0.0f);
    const float wv1 = ((z0 >= ND - 1) ? wza : 0.0f) + ((z0 >=  0) ? wzb : 0.0f);
    const float wxa = 1.0f - fx, wya = 1.0f - fy;
    float wxy[4];
    wxy[0] = wxa * wya;  wxy[1] = wxa * fy;
    wxy[2] = fx  * wya;  wxy[3] = fx  * fy;
    float wA[4], wB[4];
#pragma unroll
    for (int c = 0; c < 4; ++c) { wA[c] = wxy[c] * wv0; wB[c] = wxy[c] * wv1; }

    // ---- drain gathers, then accumulate ----
    asm volatile("s_waitcnt vmcnt(0)" ::: "memory");
    __builtin_amdgcn_sched_barrier(0);

    float acc[6] = {0.f, 0.f, 0.f, 0.f, 0.f, 0.f};
#pragma unroll
    for (int c = 0; c < 4; ++c)
#pragma unroll
        for (int ch = 0; ch < 6; ++ch)
            acc[ch] = fmaf(wA[c], g[ch][c].x, fmaf(wB[c], g[ch][c].y, acc[ch]));

    // ---- T = R^T D R, output lower-tri ----
    float Dm[3][3];
    Dm[0][0] = acc[0]; Dm[0][1] = acc[1]; Dm[0][2] = acc[3];
    Dm[1][0] = acc[1]; Dm[1][1] = acc[2]; Dm[1][2] = acc[4];
    Dm[2][0] = acc[3]; Dm[2][1] = acc[4]; Dm[2][2] = acc[5];

    float M[3][3];
#pragma unroll
    for (int i = 0; i < 3; ++i)
#pragma unroll
        for (int k = 0; k < 3; ++k)
            M[i][k] = U[0][i]*Dm[0][k] + U[1][i]*Dm[1][k] + U[2][i]*Dm[2][k];

    float T00 = M[0][0]*U[0][0] + M[0][1]*U[1][0] + M[0][2]*U[2][0];
    float T10 = M[1][0]*U[0][0] + M[1][1]*U[1][0] + M[1][2]*U[2][0];
    float T11 = M[1][0]*U[0][1] + M[1][1]*U[1][1] + M[1][2]*U[2][1];
    float T20 = M[2][0]*U[0][0] + M[2][1]*U[1][0] + M[2][2]*U[2][0];
    float T21 = M[2][0]*U[0][1] + M[2][1]*U[1][1] + M[2][2]*U[2][1];
    float T22 = M[2][0]*U[0][2] + M[2][1]*U[1][2] + M[2][2]*U[2][2];

    const int obase = b * 6 * HWD;            // scalar
    out[obase + 0 * HWD + sp] = T00;
    out[obase + 1 * HWD + sp] = T10;
    out[obase + 2 * HWD + sp] = T11;
    out[obase + 3 * HWD + sp] = T20;
    out[obase + 4 * HWD + sp] = T21;
    out[obase + 5 * HWD + sp] = T22;
}

extern "C" void kernel_launch(void* const* d_in, const int* in_sizes, int n_in,
                              void* d_out, int out_size, void* d_ws, size_t ws_size,
                              hipStream_t stream) {
    const float* dti = (const float*)d_in[0];
    const float* ddf = (const float*)d_in[1];
    float* o = (float*)d_out;
    const int n = NB * HWD;   // 4,194,304 voxels
    warp_dti_kernel<<<n / 256, 256, 0, stream>>>(dti, ddf, o);
}